// Round 7
// baseline (1425.971 us; speedup 1.0000x reference)
//
#include <hip/hip_runtime.h>

#define N_NODES 100000
#define N_EDGES 1600000
#define D 128
#define SUBW 64                       // dst-nodes per sub-bucket
#define NSUB 1563                     // ceil(N_NODES/SUBW)
#define CAP2 1408                     // per-sub capacity (mean 1024, sigma 32 -> 12 sigma)
#define CHUNK2 8192                   // edges per binC block
#define BINC_BLOCKS ((N_EDGES + CHUNK2 - 1) / CHUNK2)   // 196

typedef __attribute__((ext_vector_type(8))) short short8;
typedef __attribute__((ext_vector_type(4))) float float4v;

__device__ inline unsigned short f2bf(float f) {
    unsigned u = __float_as_uint(f);
    unsigned r = (u + 0x7fffu + ((u >> 16) & 1u)) >> 16;   // RNE
    return (unsigned short)r;
}
__device__ inline float bflo(unsigned int p) { return __uint_as_float(p << 16); }
__device__ inline float bfhi(unsigned int p) { return __uint_as_float(p & 0xffff0000u); }

// dtype probe (bf16 flag=1 / fp32 flag=0) fused with b -> fp32 conversion
__global__ void probe_convert_kernel(const unsigned int* __restrict__ xw,
                                     const void* __restrict__ b,
                                     int* __restrict__ flag, float* __restrict__ bfv) {
    __shared__ int cnt;
    if (threadIdx.x == 0) cnt = 0;
    __syncthreads();
    unsigned low = xw[threadIdx.x] & 0xFFFFu;
    unsigned e = (low >> 7) & 0xFFu;
    atomicAdd(&cnt, (int)((e == 0u) || (e >= 107u && e <= 147u)));
    __syncthreads();
    int m = (cnt >= 192);
    if (threadIdx.x == 0) *flag = m;
    if (threadIdx.x < D)
        bfv[threadIdx.x] = m ? bflo(((const unsigned short*)b)[threadIdx.x])
                             : ((const float*)b)[threadIdx.x];
}

// Fine-bin edges by sub-bucket (sub = dst>>6) in ONE pass; fold deg counting in.
// Record = src(17b) | (dst&63)<<17 packed into 4 B. Block-private appends via
// LDS histogram: ~1563 return-atomics per BLOCK (not per edge — R4/R6 lesson).
__global__ void binC_kernel(const int* __restrict__ src, const int* __restrict__ dst,
                            int* __restrict__ subcnt, int* __restrict__ deg,
                            unsigned* __restrict__ rec2) {
    __shared__ int lcnt[NSUB];
    __shared__ int lbase[NSUB];
    int tid = threadIdx.x;
    int e0 = blockIdx.x * CHUNK2;
    int e1 = e0 + CHUNK2 < N_EDGES ? e0 + CHUNK2 : N_EDGES;
    for (int s = tid; s < NSUB; s += 256) lcnt[s] = 0;
    __syncthreads();
    for (int i = e0 + tid; i < e1; i += 256) {
        int d = dst[i];
        atomicAdd(&lcnt[d >> 6], 1);
        atomicAdd(&deg[d], 1);
    }
    __syncthreads();
    for (int s = tid; s < NSUB; s += 256) {
        int c = lcnt[s];
        lbase[s] = c ? atomicAdd(&subcnt[s], c) : 0;
        lcnt[s] = 0;
    }
    __syncthreads();
    for (int i = e0 + tid; i < e1; i += 256) {
        int d = dst[i], s = src[i];
        int sub = d >> 6;
        int pos = lbase[sub] + atomicAdd(&lcnt[sub], 1);
        if (pos < CAP2)
            rec2[(size_t)sub * CAP2 + pos] = (unsigned)s | ((unsigned)(d & 63) << 17);
    }
}

// h' = (x @ W) * rsqrt(deg+1) -> bf16 bits. MFMA 16x16x32 bf16, one wave per 16-row strip.
__global__ void gemm_kernel(const void* __restrict__ xv, const void* __restrict__ Wv,
                            const int* __restrict__ flag, const int* __restrict__ deg,
                            unsigned short* __restrict__ h) {
    __shared__ unsigned short Wt[D * 136];  // W transposed [col][k], stride 136
    int tid = threadIdx.x;
    int m = *flag;
    for (int idx = tid; idx < D * D; idx += 256) {
        int k = idx >> 7, c = idx & 127;
        Wt[c * 136 + k] = m ? ((const unsigned short*)Wv)[idx]
                            : f2bf(((const float*)Wv)[idx]);
    }
    __syncthreads();

    int wave = tid >> 6, lane = tid & 63;
    int row0 = (blockIdx.x * 4 + wave) * 16;
    if (row0 >= N_NODES) return;
    int r = lane & 15, quad = lane >> 4;

    short8 a[4];  // a[t][j] = x[row0+r][t*32 + quad*8 + j]
    if (m) {
        const unsigned short* xr = (const unsigned short*)xv + (size_t)(row0 + r) * D + quad * 8;
        #pragma unroll
        for (int t = 0; t < 4; ++t) a[t] = *(const short8*)(xr + t * 32);
    } else {
        const float* xr = (const float*)xv + (size_t)(row0 + r) * D + quad * 8;
        #pragma unroll
        for (int t = 0; t < 4; ++t)
            for (int j = 0; j < 8; ++j) a[t][j] = (short)f2bf(xr[t * 32 + j]);
    }

    float sc[4];
    #pragma unroll
    for (int reg = 0; reg < 4; ++reg)
        sc[reg] = rsqrtf((float)(deg[row0 + quad * 4 + reg] + 1));

    #pragma unroll
    for (int ct = 0; ct < 8; ++ct) {
        int col0 = ct * 16;
        float4v c = {0.f, 0.f, 0.f, 0.f};
        #pragma unroll
        for (int t = 0; t < 4; ++t) {
            short8 bfr = *(const short8*)&Wt[(col0 + r) * 136 + t * 32 + quad * 8];
            c = __builtin_amdgcn_mfma_f32_16x16x32_bf16(a[t], bfr, c, 0, 0, 0);
        }
        #pragma unroll
        for (int reg = 0; reg < 4; ++reg) {
            int orow = row0 + quad * 4 + reg;  // C/D: col=lane&15, row=quad*4+reg
            h[(size_t)orow * D + col0 + r] = f2bf(c[reg] * sc[reg]);
        }
    }
}

// One block per sub-bucket: LDS fp32 acc[64 nodes][128 cols]; per edge, 64 lanes load
// the 256-B h' row (1 dword/lane, fully coalesced) and ds_add into LDS. Epilogue fuses
// self-loop + rsqrt + bias + ReLU + coalesced store.
__global__ void __launch_bounds__(256) aggregate2_kernel(
        const unsigned* __restrict__ rec2, const int* __restrict__ subcnt,
        const int* __restrict__ deg, const float* __restrict__ bfv,
        const int* __restrict__ flag, const unsigned short* __restrict__ h,
        void* __restrict__ out) {
    __shared__ float lacc[SUBW * D];   // 32 KB
    __shared__ float ldis[SUBW];
    int sub = blockIdx.x;
    int tid = threadIdx.x;
    int n0 = sub * SUBW;

    {
        float4* z = (float4*)lacc;
        for (int i = tid; i < SUBW * D / 4; i += 256) z[i] = make_float4(0.f, 0.f, 0.f, 0.f);
    }
    if (tid < SUBW) {
        int n = n0 + tid;
        ldis[tid] = (n < N_NODES) ? rsqrtf((float)(deg[n] + 1)) : 0.f;
    }
    __syncthreads();

    int count = subcnt[sub]; if (count > CAP2) count = CAP2;
    const unsigned* r = rec2 + (size_t)sub * CAP2;
    const unsigned* hw = (const unsigned*)h;      // dword view: row n = 64 dwords
    int wave = tid >> 6, lane = tid & 63;
    int len = (count + 3) >> 2;
    int start = wave * len;
    int end = start + len < count ? start + len : count;
    int c2 = lane * 2;

    int e = start;
    for (; e + 4 <= end; e += 4) {
        unsigned w0 = r[e], w1 = r[e + 1], w2 = r[e + 2], w3 = r[e + 3];
        unsigned p0 = hw[(size_t)(w0 & 0x1FFFFu) * 64 + lane];
        unsigned p1 = hw[(size_t)(w1 & 0x1FFFFu) * 64 + lane];
        unsigned p2 = hw[(size_t)(w2 & 0x1FFFFu) * 64 + lane];
        unsigned p3 = hw[(size_t)(w3 & 0x1FFFFu) * 64 + lane];
        atomicAdd(&lacc[((w0 >> 17) & 63) * D + c2],     bflo(p0));
        atomicAdd(&lacc[((w0 >> 17) & 63) * D + c2 + 1], bfhi(p0));
        atomicAdd(&lacc[((w1 >> 17) & 63) * D + c2],     bflo(p1));
        atomicAdd(&lacc[((w1 >> 17) & 63) * D + c2 + 1], bfhi(p1));
        atomicAdd(&lacc[((w2 >> 17) & 63) * D + c2],     bflo(p2));
        atomicAdd(&lacc[((w2 >> 17) & 63) * D + c2 + 1], bfhi(p2));
        atomicAdd(&lacc[((w3 >> 17) & 63) * D + c2],     bflo(p3));
        atomicAdd(&lacc[((w3 >> 17) & 63) * D + c2 + 1], bfhi(p3));
    }
    for (; e < end; ++e) {
        unsigned w0 = r[e];
        unsigned p0 = hw[(size_t)(w0 & 0x1FFFFu) * 64 + lane];
        atomicAdd(&lacc[((w0 >> 17) & 63) * D + c2],     bflo(p0));
        atomicAdd(&lacc[((w0 >> 17) & 63) * D + c2 + 1], bfhi(p0));
    }
    __syncthreads();

    int m = *flag;
    if (m) {
        unsigned* ob = (unsigned*)out;              // bf16 row n = 64 uints
        for (int u = tid; u < SUBW * 64; u += 256) {
            int nl = u >> 6, cp = u & 63;
            int n = n0 + nl;
            if (n < N_NODES) {
                unsigned sp = hw[(size_t)n * 64 + cp];
                float dn = ldis[nl];
                float v0 = fmaxf(dn * (lacc[nl * D + 2 * cp]     + bflo(sp)) + bfv[2 * cp],     0.f);
                float v1 = fmaxf(dn * (lacc[nl * D + 2 * cp + 1] + bfhi(sp)) + bfv[2 * cp + 1], 0.f);
                ob[(size_t)n * 64 + cp] = ((unsigned)f2bf(v1) << 16) | (unsigned)f2bf(v0);
            }
        }
    } else {
        float* of = (float*)out;
        for (int v = tid; v < SUBW * D; v += 256) {
            int nl = v >> 7, col = v & 127;
            int n = n0 + nl;
            if (n < N_NODES) {
                unsigned sp = hw[(size_t)n * 64 + (col >> 1)];
                float sv = (col & 1) ? bfhi(sp) : bflo(sp);
                float val = ldis[nl] * (lacc[nl * D + col] + sv) + bfv[col];
                of[(size_t)n * D + col] = fmaxf(val, 0.f);
            }
        }
    }
}

extern "C" void kernel_launch(void* const* d_in, const int* in_sizes, int n_in,
                              void* d_out, int out_size, void* d_ws, size_t ws_size,
                              hipStream_t stream) {
    const void* x = nullptr; const int* ei = nullptr;
    const void* W = nullptr; const void* b = nullptr;
    for (int i = 0; i < n_in; ++i) {
        if      (in_sizes[i] == N_NODES * D) x  = d_in[i];
        else if (in_sizes[i] == 2 * N_EDGES) ei = (const int*)d_in[i];
        else if (in_sizes[i] == D * D)       W  = d_in[i];
        else if (in_sizes[i] == D)           b  = d_in[i];
    }
    if (!x || !ei || !W || !b) {
        x = d_in[0]; ei = (const int*)d_in[1]; W = d_in[2]; b = d_in[3];
    }
    const int* src = ei;            // edge_index[0]
    const int* dst = ei + N_EDGES;  // edge_index[1]

    // ws: flag(16B) | subcnt NSUB(+pad to 1564) | deg N | bfv 128 f32 | rec2 NSUB*CAP2 u32 |
    //     h N*D bf16   (~35 MB)
    char* ws = (char*)d_ws;
    int*      flag   = (int*)ws;
    int*      subcnt = (int*)(ws + 16);
    int*      deg    = subcnt + 1564;                 // NSUB=1563 rounded to mult-of-4
    float*    bfv    = (float*)(deg + N_NODES);
    unsigned* rec2   = (unsigned*)(bfv + D);
    unsigned short* h = (unsigned short*)(rec2 + (size_t)NSUB * CAP2);

    // subcnt and deg are contiguous -> single memset
    hipMemsetAsync(subcnt, 0, sizeof(int) * (1564 + N_NODES), stream);

    probe_convert_kernel<<<1, 256, 0, stream>>>((const unsigned int*)x, b, flag, bfv);

    binC_kernel<<<BINC_BLOCKS, 256, 0, stream>>>(src, dst, subcnt, deg, rec2);

    gemm_kernel<<<(N_NODES + 63) / 64, 256, 0, stream>>>(x, W, flag, deg, h);

    aggregate2_kernel<<<NSUB, 256, 0, stream>>>(rec2, subcnt, deg, bfv, flag, h, d_out);
}

// Round 8
// 307.046 us; speedup vs baseline: 4.6442x; 4.6442x over previous
//
#include <hip/hip_runtime.h>

#define N_NODES 100000
#define N_EDGES 1600000
#define D 128
#define SUBW 64                       // dst-nodes per sub-bucket
#define NSUB 1563                     // ceil(N_NODES/SUBW)
#define CAP2 1408                     // per-sub capacity (mean 1024, sigma ~32 -> +12 sigma)
#define CHUNK2 8192                   // edges per binC block
#define BINC_BLOCKS ((N_EDGES + CHUNK2 - 1) / CHUNK2)   // 196

typedef __attribute__((ext_vector_type(8))) short short8;
typedef __attribute__((ext_vector_type(4))) float float4v;

__device__ inline unsigned short f2bf(float f) {
    unsigned u = __float_as_uint(f);
    unsigned r = (u + 0x7fffu + ((u >> 16) & 1u)) >> 16;   // RNE
    return (unsigned short)r;
}
__device__ inline float bflo(unsigned int p) { return __uint_as_float(p << 16); }
__device__ inline float bfhi(unsigned int p) { return __uint_as_float(p & 0xffff0000u); }

// dtype probe (bf16 flag=1 / fp32 flag=0) fused with b -> fp32 conversion
__global__ void probe_convert_kernel(const unsigned int* __restrict__ xw,
                                     const void* __restrict__ b,
                                     int* __restrict__ flag, float* __restrict__ bfv) {
    __shared__ int cnt;
    if (threadIdx.x == 0) cnt = 0;
    __syncthreads();
    unsigned low = xw[threadIdx.x] & 0xFFFFu;
    unsigned e = (low >> 7) & 0xFFu;
    atomicAdd(&cnt, (int)((e == 0u) || (e >= 107u && e <= 147u)));
    __syncthreads();
    int m = (cnt >= 192);
    if (threadIdx.x == 0) *flag = m;
    if (threadIdx.x < D)
        bfv[threadIdx.x] = m ? bflo(((const unsigned short*)b)[threadIdx.x])
                             : ((const float*)b)[threadIdx.x];
}

// Fine-bin edges by sub-bucket (sub = dst>>6) in ONE pass; fold deg counting in.
// Record = src(17b) | (dst&63)<<17 in 4 B. Per-BLOCK return-atomics only (R4/R6 lesson).
// INT LDS atomics only — native ds_add (fp32 LDS atomics CAS-loop at ~13x cost, R7 lesson).
__global__ void binC_kernel(const int* __restrict__ src, const int* __restrict__ dst,
                            int* __restrict__ subcnt, int* __restrict__ deg,
                            unsigned* __restrict__ rec2) {
    __shared__ int lcnt[NSUB];
    __shared__ int lbase[NSUB];
    int tid = threadIdx.x;
    int e0 = blockIdx.x * CHUNK2;
    int e1 = e0 + CHUNK2 < N_EDGES ? e0 + CHUNK2 : N_EDGES;
    for (int s = tid; s < NSUB; s += 256) lcnt[s] = 0;
    __syncthreads();
    for (int i = e0 + tid; i < e1; i += 256) {
        int d = dst[i];
        atomicAdd(&lcnt[d >> 6], 1);
        atomicAdd(&deg[d], 1);
    }
    __syncthreads();
    for (int s = tid; s < NSUB; s += 256) {
        int c = lcnt[s];
        lbase[s] = c ? atomicAdd(&subcnt[s], c) : 0;
        lcnt[s] = 0;
    }
    __syncthreads();
    for (int i = e0 + tid; i < e1; i += 256) {
        int d = dst[i], s = src[i];
        int sub = d >> 6;
        int pos = lbase[sub] + atomicAdd(&lcnt[sub], 1);
        if (pos < CAP2)
            rec2[(size_t)sub * CAP2 + pos] = (unsigned)s | ((unsigned)(d & 63) << 17);
    }
}

// h' = (x @ W) * rsqrt(deg+1) -> bf16 bits. MFMA 16x16x32 bf16, one wave per 16-row strip.
__global__ void gemm_kernel(const void* __restrict__ xv, const void* __restrict__ Wv,
                            const int* __restrict__ flag, const int* __restrict__ deg,
                            unsigned short* __restrict__ h) {
    __shared__ unsigned short Wt[D * 136];  // W transposed [col][k], stride 136
    int tid = threadIdx.x;
    int m = *flag;
    for (int idx = tid; idx < D * D; idx += 256) {
        int k = idx >> 7, c = idx & 127;
        Wt[c * 136 + k] = m ? ((const unsigned short*)Wv)[idx]
                            : f2bf(((const float*)Wv)[idx]);
    }
    __syncthreads();

    int wave = tid >> 6, lane = tid & 63;
    int row0 = (blockIdx.x * 4 + wave) * 16;
    if (row0 >= N_NODES) return;
    int r = lane & 15, quad = lane >> 4;

    short8 a[4];  // a[t][j] = x[row0+r][t*32 + quad*8 + j]
    if (m) {
        const unsigned short* xr = (const unsigned short*)xv + (size_t)(row0 + r) * D + quad * 8;
        #pragma unroll
        for (int t = 0; t < 4; ++t) a[t] = *(const short8*)(xr + t * 32);
    } else {
        const float* xr = (const float*)xv + (size_t)(row0 + r) * D + quad * 8;
        #pragma unroll
        for (int t = 0; t < 4; ++t)
            for (int j = 0; j < 8; ++j) a[t][j] = (short)f2bf(xr[t * 32 + j]);
    }

    float sc[4];
    #pragma unroll
    for (int reg = 0; reg < 4; ++reg)
        sc[reg] = rsqrtf((float)(deg[row0 + quad * 4 + reg] + 1));

    #pragma unroll
    for (int ct = 0; ct < 8; ++ct) {
        int col0 = ct * 16;
        float4v c = {0.f, 0.f, 0.f, 0.f};
        #pragma unroll
        for (int t = 0; t < 4; ++t) {
            short8 bfr = *(const short8*)&Wt[(col0 + r) * 136 + t * 32 + quad * 8];
            c = __builtin_amdgcn_mfma_f32_16x16x32_bf16(a[t], bfr, c, 0, 0, 0);
        }
        #pragma unroll
        for (int reg = 0; reg < 4; ++reg) {
            int orow = row0 + quad * 4 + reg;  // C/D: col=lane&15, row=quad*4+reg
            h[(size_t)orow * D + col0 + r] = f2bf(c[reg] * sc[reg]);
        }
    }
}

// One block per sub-bucket: LDS counting-sort of records by local node, then the
// R6-measured register-accumulate gather (quarter-wave uint4, 4 edges in flight),
// butterfly combine, fused self+rsqrt+bias+relu epilogue. NO fp32 LDS atomics.
__global__ void __launch_bounds__(256) agg3_kernel(
        const unsigned* __restrict__ rec2, const int* __restrict__ subcnt,
        const float* __restrict__ bfv, const int* __restrict__ flag,
        const unsigned short* __restrict__ h, void* __restrict__ out) {
    __shared__ unsigned srt[CAP2];     // sorted src indices (5.6 KB)
    __shared__ int hist[SUBW];
    __shared__ int ofs[SUBW];
    __shared__ int place[SUBW];
    __shared__ float lbias[D];

    int sub = blockIdx.x, tid = threadIdx.x;
    int n0 = sub * SUBW;
    if (tid < SUBW) hist[tid] = 0;
    if (tid < D) lbias[tid] = bfv[tid];
    __syncthreads();

    int count = subcnt[sub]; if (count > CAP2) count = CAP2;
    const unsigned* r = rec2 + (size_t)sub * CAP2;

    for (int i = tid; i < count; i += 256)
        atomicAdd(&hist[(r[i] >> 17) & 63], 1);          // int LDS atomic: native
    __syncthreads();
    if (tid == 0) {
        int s = 0;
        for (int k = 0; k < SUBW; ++k) { ofs[k] = s; place[k] = s; s += hist[k]; }
    }
    __syncthreads();
    for (int i = tid; i < count; i += 256) {
        unsigned w = r[i];
        int p = atomicAdd(&place[(w >> 17) & 63], 1);
        srt[p] = w & 0x1FFFFu;
    }
    __syncthreads();

    const uint4* h4 = (const uint4*)h;                   // h row = 16 uint4
    int wave = tid >> 6, lane = tid & 63;
    int q = lane >> 4, c16 = lane & 15;
    int m = *flag;

    for (int t = 0; t < 16; ++t) {
        int nl = wave * 16 + t;
        int n = n0 + nl;
        if (n >= N_NODES) break;
        int o = ofs[nl], cnt = hist[nl];
        int e_end = o + cnt;

        float acc[8] = {0.f, 0.f, 0.f, 0.f, 0.f, 0.f, 0.f, 0.f};
        for (int j = o + q; j < e_end; j += 4) {
            unsigned s = srt[j];                         // same-addr LDS read: broadcast
            uint4 p = h4[(size_t)s * 16 + c16];
            acc[0] += bflo(p.x); acc[1] += bfhi(p.x);
            acc[2] += bflo(p.y); acc[3] += bfhi(p.y);
            acc[4] += bflo(p.z); acc[5] += bfhi(p.z);
            acc[6] += bflo(p.w); acc[7] += bfhi(p.w);
        }
        #pragma unroll
        for (int i = 0; i < 8; ++i) {
            acc[i] += __shfl_xor(acc[i], 16);
            acc[i] += __shfl_xor(acc[i], 32);
        }

        if (q == 0) {
            uint4 sp = h4[(size_t)n * 16 + c16];         // self term (dis[src] folded in h')
            float dn = rsqrtf((float)(cnt + 1));
            float v[8];
            v[0] = fmaxf(dn * (acc[0] + bflo(sp.x)) + lbias[c16 * 8 + 0], 0.f);
            v[1] = fmaxf(dn * (acc[1] + bfhi(sp.x)) + lbias[c16 * 8 + 1], 0.f);
            v[2] = fmaxf(dn * (acc[2] + bflo(sp.y)) + lbias[c16 * 8 + 2], 0.f);
            v[3] = fmaxf(dn * (acc[3] + bfhi(sp.y)) + lbias[c16 * 8 + 3], 0.f);
            v[4] = fmaxf(dn * (acc[4] + bflo(sp.z)) + lbias[c16 * 8 + 4], 0.f);
            v[5] = fmaxf(dn * (acc[5] + bfhi(sp.z)) + lbias[c16 * 8 + 5], 0.f);
            v[6] = fmaxf(dn * (acc[6] + bflo(sp.w)) + lbias[c16 * 8 + 6], 0.f);
            v[7] = fmaxf(dn * (acc[7] + bfhi(sp.w)) + lbias[c16 * 8 + 7], 0.f);
            if (m) {
                uint4 pk;
                pk.x = ((unsigned)f2bf(v[1]) << 16) | f2bf(v[0]);
                pk.y = ((unsigned)f2bf(v[3]) << 16) | f2bf(v[2]);
                pk.z = ((unsigned)f2bf(v[5]) << 16) | f2bf(v[4]);
                pk.w = ((unsigned)f2bf(v[7]) << 16) | f2bf(v[6]);
                ((uint4*)out)[(size_t)n * 16 + c16] = pk;
            } else {
                float4 f0 = make_float4(v[0], v[1], v[2], v[3]);
                float4 f1 = make_float4(v[4], v[5], v[6], v[7]);
                float4* of = (float4*)((float*)out + (size_t)n * D + c16 * 8);
                of[0] = f0; of[1] = f1;
            }
        }
    }
}

extern "C" void kernel_launch(void* const* d_in, const int* in_sizes, int n_in,
                              void* d_out, int out_size, void* d_ws, size_t ws_size,
                              hipStream_t stream) {
    const void* x = nullptr; const int* ei = nullptr;
    const void* W = nullptr; const void* b = nullptr;
    for (int i = 0; i < n_in; ++i) {
        if      (in_sizes[i] == N_NODES * D) x  = d_in[i];
        else if (in_sizes[i] == 2 * N_EDGES) ei = (const int*)d_in[i];
        else if (in_sizes[i] == D * D)       W  = d_in[i];
        else if (in_sizes[i] == D)           b  = d_in[i];
    }
    if (!x || !ei || !W || !b) {
        x = d_in[0]; ei = (const int*)d_in[1]; W = d_in[2]; b = d_in[3];
    }
    const int* src = ei;            // edge_index[0]
    const int* dst = ei + N_EDGES;  // edge_index[1]

    // ws: flag(16B) | subcnt 1564 | deg N | bfv 128 f32 | rec2 NSUB*CAP2 u32 | h N*D bf16
    char* ws = (char*)d_ws;
    int*      flag   = (int*)ws;
    int*      subcnt = (int*)(ws + 16);
    int*      deg    = subcnt + 1564;
    float*    bfv    = (float*)(deg + N_NODES);
    unsigned* rec2   = (unsigned*)(bfv + D);
    unsigned short* h = (unsigned short*)(rec2 + (size_t)NSUB * CAP2);

    hipMemsetAsync(subcnt, 0, sizeof(int) * (1564 + N_NODES), stream);

    probe_convert_kernel<<<1, 256, 0, stream>>>((const unsigned int*)x, b, flag, bfv);

    binC_kernel<<<BINC_BLOCKS, 256, 0, stream>>>(src, dst, subcnt, deg, rec2);

    gemm_kernel<<<(N_NODES + 63) / 64, 256, 0, stream>>>(x, W, flag, deg, h);

    agg3_kernel<<<NSUB, 256, 0, stream>>>(rec2, subcnt, bfv, flag, h, d_out);
}